// Round 15
// baseline (253.032 us; speedup 1.0000x reference)
//
#include <hip/hip_runtime.h>

#define HW 256
#define BATCH 8
#define C 64
#define HO 244
#define NPAD 192
#define KTOT 576

typedef __bf16 bf16x8 __attribute__((ext_vector_type(8)));
typedef float f32x16 __attribute__((ext_vector_type(16)));
typedef float f32x2 __attribute__((ext_vector_type(2)));
typedef unsigned short us8 __attribute__((ext_vector_type(8)));

// native RNE float->bf16 (v_cvt_pk_bf16_f32 capable)
__device__ inline unsigned short fbf(float f) {
    return __builtin_bit_cast(unsigned short, (__bf16)f);
}

__device__ inline float bf2f(unsigned short s) {
    union { unsigned int u; float f; } c;
    c.u = ((unsigned int)s) << 16;
    return c.f;
}

// ---- merged W2+W3 repack, fragment-coalesced: [((kstep*2+khalf)*N + n)*8 + e] ----
__global__ __launch_bounds__(256) void repack_w_kernel(
    const float* __restrict__ W2, const float* __restrict__ W3,
    unsigned short* __restrict__ B2g, unsigned short* __restrict__ B3g)
{
    int idx = blockIdx.x * 256 + threadIdx.x;
    if (idx < 36 * 2 * C * 8) {
        int e = idx & 7;
        int r = idx >> 3;
        int n = r & 63;
        int s = r >> 6;
        int khalf = s & 1;
        int kstep = s >> 1;
        int chunk = kstep >> 2, ks = kstep & 3;
        int ci = ks * 16 + khalf * 8 + e;
        B2g[idx] = fbf(W2[((size_t)n * C + ci) * 9 + chunk]);
    } else {
        int j = idx - 36 * 2 * C * 8;
        if (j >= 36 * 2 * NPAD * 8) return;
        int e = j & 7;
        int r = j >> 3;
        int n = r % NPAD;
        int s = r / NPAD;
        int khalf = s & 1;
        int kstep = s >> 1;
        int chunk = kstep >> 2, ks = kstep & 3;
        int ci = ks * 16 + khalf * 8 + e;
        float v = (n < 169) ? W3[((size_t)n * C + ci) * 9 + chunk] : 0.f;
        B3g[j] = fbf(v);
    }
}

// ---------------- fused conv1+conv2 (r12 form, single dispatch) ----------------
__global__ __launch_bounds__(256, 3) void conv2_fused_kernel(
    const float* __restrict__ x, const float* __restrict__ W1,
    const float* __restrict__ b1, const unsigned short* __restrict__ W2r,
    const float* __restrict__ b2, unsigned short* __restrict__ h2)
{
    __shared__ unsigned short Ash[396 * 66];   // 52,272 B
    __shared__ unsigned short Xsh[8 * 68];     //  1,088 B (bf16)

    const int t = threadIdx.x;
    const int lane = t & 63;
    const int wave = t >> 6;
    const int b  = blockIdx.z;
    const int h0 = blockIdx.y * 4;
    const int w0 = blockIdx.x * 64;

    const int col   = lane & 31;
    const int khalf = lane >> 5;
    const int mrow_base = wave * 64;

    // ---- stage x tile (bf16): rows h0-2..h0+5, cols w0-2..w0+65, zero OOB ----
    const float* __restrict__ xplane = x + ((size_t)b << 16);
#pragma unroll
    for (int it = 0; it < 3; ++it) {
        int li = it * 256 + t;
        if (li < 8 * 68) {
            int rr = li / 68, cc = li - rr * 68;
            int hh = h0 - 2 + rr, ww = w0 - 2 + cc;
            bool ok = (hh >= 0) && (hh < HW) && (ww >= 0) && (ww < HW);
            Xsh[li] = ok ? fbf(xplane[hh * HW + ww]) : (unsigned short)0;
        }
    }

    // this thread's 4 channels as two float2 pairs (packed-math path)
    const int g4 = t & 15;
    f32x2 w01[9], w23[9];
    f32x2 bia01, bia23;
    bia01[0] = b1[g4 * 4 + 0]; bia01[1] = b1[g4 * 4 + 1];
    bia23[0] = b1[g4 * 4 + 2]; bia23[1] = b1[g4 * 4 + 3];
#pragma unroll
    for (int q = 0; q < 9; ++q) {
        w01[q][0] = W1[(g4 * 4 + 0) * 9 + q];
        w01[q][1] = W1[(g4 * 4 + 1) * 9 + q];
        w23[q][0] = W1[(g4 * 4 + 2) * 9 + q];
        w23[q][1] = W1[(g4 * 4 + 3) * 9 + q];
    }

    __syncthreads();   // Xsh ready

    // ---- compute h1 tile (conv1 + ReLU + bf16) into Ash ----
    for (int it = 0; it < 25; ++it) {
        int li = it * 256 + t;
        if (li < 6336) {
            int p = li >> 4;
            int pr = p / 66, pc = p - pr * 66;
            int hh = h0 - 1 + pr, ww = w0 - 1 + pc;
            unsigned short ov[4];
            if (hh >= 0 && hh < HW && ww >= 0 && ww < HW) {
                const unsigned short* xb = Xsh + pr * 68 + pc;
                f32x2 a01 = bia01, a23 = bia23;
#pragma unroll
                for (int i = 0; i < 3; ++i)
#pragma unroll
                    for (int j = 0; j < 3; ++j) {
                        float xv = bf2f(xb[i * 68 + j]);
                        f32x2 xv2; xv2[0] = xv; xv2[1] = xv;
                        a01 += xv2 * w01[i * 3 + j];
                        a23 += xv2 * w23[i * 3 + j];
                    }
                ov[0] = fbf(fmaxf(a01[0], 0.f));
                ov[1] = fbf(fmaxf(a01[1], 0.f));
                ov[2] = fbf(fmaxf(a23[0], 0.f));
                ov[3] = fbf(fmaxf(a23[1], 0.f));
            } else {
#pragma unroll
                for (int u = 0; u < 4; ++u) ov[u] = 0;
            }
            *(uint2*)(Ash + p * 66 + g4 * 4) = *(uint2*)ov;
        }
    }

    const unsigned short* bbase = W2r + ((size_t)khalf * C + col) * 8;
    us8 bc0 = *(const us8*)(bbase);
    us8 bc1 = *(const us8*)(bbase + 32 * 8);

    f32x16 acc[2][2];
#pragma unroll
    for (int ai = 0; ai < 2; ++ai)
#pragma unroll
        for (int nb = 0; nb < 2; ++nb)
#pragma unroll
            for (int r = 0; r < 16; ++r) acc[ai][nb][r] = 0.f;

    __syncthreads();   // Ash ready

#pragma unroll
    for (int chunk = 0; chunk < 9; ++chunk) {
        const int ii = chunk / 3, jj = chunk - ii * 3;
        const int pixbase = (wave + ii) * 66 + jj;
#pragma unroll
        for (int ks = 0; ks < 4; ++ks) {
            const int kstep = chunk * 4 + ks;
            us8 bn0, bn1;
            if (kstep < 35) {
                const unsigned short* bp = bbase + (size_t)(kstep + 1) * (2 * C * 8);
                bn0 = *(const us8*)(bp);
                bn1 = *(const us8*)(bp + 32 * 8);
            }
            const int koff = ks * 16 + khalf * 8;
            bf16x8 a0 = __builtin_bit_cast(bf16x8, *(const us8*)(Ash + (pixbase + col) * 66 + koff));
            bf16x8 a1 = __builtin_bit_cast(bf16x8, *(const us8*)(Ash + (pixbase + col + 32) * 66 + koff));
            bf16x8 v0 = __builtin_bit_cast(bf16x8, bc0);
            bf16x8 v1 = __builtin_bit_cast(bf16x8, bc1);
            acc[0][0] = __builtin_amdgcn_mfma_f32_32x32x16_bf16(a0, v0, acc[0][0], 0, 0, 0);
            acc[0][1] = __builtin_amdgcn_mfma_f32_32x32x16_bf16(a0, v1, acc[0][1], 0, 0, 0);
            acc[1][0] = __builtin_amdgcn_mfma_f32_32x32x16_bf16(a1, v0, acc[1][0], 0, 0, 0);
            acc[1][1] = __builtin_amdgcn_mfma_f32_32x32x16_bf16(a1, v1, acc[1][1], 0, 0, 0);
            bc0 = bn0; bc1 = bn1;
        }
    }

#pragma unroll
    for (int nb = 0; nb < 2; ++nb) {
        const int n = nb * 32 + col;
        const float bias = b2[n];
#pragma unroll
        for (int ai = 0; ai < 2; ++ai) {
#pragma unroll
            for (int r = 0; r < 16; ++r) {
                int m = mrow_base + ai * 32 + (r & 3) + ((r >> 2) << 3) + (khalf << 2);
                int h = h0 + (m >> 6), w = w0 + (m & 63);
                float val = fmaxf(acc[ai][nb][r] + bias, 0.f);
                h2[(((size_t)b * HW + h) * HW + w) * C + n] = fbf(val);
            }
        }
    }
}

// ---------------- conv3 + NLM (r12 math; b_off for split launch) ---------------
__global__ __launch_bounds__(512, 3) void conv3_mfma_kernel(
    const float* __restrict__ x, const unsigned short* __restrict__ h2,
    const unsigned short* __restrict__ Bg, const float* __restrict__ b3,
    float* __restrict__ y, int b_off)
{
    __shared__ unsigned short Ash[396 * 72];
    __shared__ float Xsh[16 * 77];
    __shared__ float red[8][64];

    const int t = threadIdx.x;
    const int lane = t & 63;
    const int wave = t >> 6;
    const int b   = blockIdx.z + b_off;
    const int ho0 = blockIdx.y * 4;
    const int wo0 = blockIdx.x * 64;

    const int col   = lane & 31;
    const int khalf = lane >> 5;
    const int rsel      = wave >> 1;
    const int mrow_base = rsel * 64;
    const int nbase     = (wave & 1) * 96;

    f32x16 acc[2][3];
#pragma unroll
    for (int mi = 0; mi < 2; ++mi)
#pragma unroll
        for (int ni = 0; ni < 3; ++ni)
#pragma unroll
            for (int r = 0; r < 16; ++r) acc[mi][ni][r] = 0.f;

#pragma unroll
    for (int it = 0; it < 7; ++it) {
        int li = it * 512 + t;
        if (li < 396 * 8) {
            int p = li >> 3, g = li & 7;
            int row = p / 66, cl = p - row * 66;
            int ww = wo0 + 5 + cl; ww = ww < 255 ? ww : 255;
            size_t src = (((size_t)b * HW + (ho0 + 5 + row)) * HW + ww) * C + g * 8;
            *(uint4*)(Ash + p * 72 + g * 8) = *(const uint4*)(h2 + src);
        }
    }
    {
        const float* __restrict__ xplane = x + ((size_t)b << 16);
#pragma unroll
        for (int it = 0; it < 3; ++it) {
            int li = it * 512 + t;
            if (li < 16 * 76) {
                int rr = li / 76, cc = li - rr * 76;
                int ww = wo0 + cc; ww = ww < 255 ? ww : 255;
                Xsh[rr * 77 + cc] = xplane[(ho0 + rr) * HW + ww];
            }
        }
    }

    const unsigned short* bbase = Bg + ((size_t)khalf * NPAD + nbase + col) * 8;
    us8 bc0 = *(const us8*)(bbase);
    us8 bc1 = *(const us8*)(bbase + 32 * 8);
    us8 bc2 = *(const us8*)(bbase + 64 * 8);

    __syncthreads();

#pragma unroll
    for (int chunk = 0; chunk < 9; ++chunk) {
        const int ii = chunk / 3, jj = chunk - ii * 3;
        const int pixbase = (rsel + ii) * 66 + jj;
#pragma unroll
        for (int ks = 0; ks < 4; ++ks) {
            const int kstep = chunk * 4 + ks;
            us8 bn0, bn1, bn2;
            if (kstep < 35) {
                const unsigned short* bp = bbase + (size_t)(kstep + 1) * (2 * NPAD * 8);
                bn0 = *(const us8*)(bp);
                bn1 = *(const us8*)(bp + 32 * 8);
                bn2 = *(const us8*)(bp + 64 * 8);
            }
            const int koff = ks * 16 + khalf * 8;
            bf16x8 a0 = __builtin_bit_cast(bf16x8, *(const us8*)(Ash + (pixbase + col) * 72 + koff));
            bf16x8 a1 = __builtin_bit_cast(bf16x8, *(const us8*)(Ash + (pixbase + col + 32) * 72 + koff));
            bf16x8 v0 = __builtin_bit_cast(bf16x8, bc0);
            bf16x8 v1 = __builtin_bit_cast(bf16x8, bc1);
            bf16x8 v2 = __builtin_bit_cast(bf16x8, bc2);
            acc[0][0] = __builtin_amdgcn_mfma_f32_32x32x16_bf16(a0, v0, acc[0][0], 0, 0, 0);
            acc[0][1] = __builtin_amdgcn_mfma_f32_32x32x16_bf16(a0, v1, acc[0][1], 0, 0, 0);
            acc[0][2] = __builtin_amdgcn_mfma_f32_32x32x16_bf16(a0, v2, acc[0][2], 0, 0, 0);
            acc[1][0] = __builtin_amdgcn_mfma_f32_32x32x16_bf16(a1, v0, acc[1][0], 0, 0, 0);
            acc[1][1] = __builtin_amdgcn_mfma_f32_32x32x16_bf16(a1, v1, acc[1][1], 0, 0, 0);
            acc[1][2] = __builtin_amdgcn_mfma_f32_32x32x16_bf16(a1, v2, acc[1][2], 0, 0, 0);
            bc0 = bn0; bc1 = bn1; bc2 = bn2;
        }
    }

    int   qv[3], uo[3], vo[3];
    float b3v[3];
#pragma unroll
    for (int ni = 0; ni < 3; ++ni) {
        int q = nbase + ni * 32 + col;
        qv[ni] = q;
        int u = q / 13;
        uo[ni] = u;
        vo[ni] = q - u * 13;
        b3v[ni] = (q < 169) ? b3[q] : 0.f;
    }

    float partial[2][16];
#pragma unroll
    for (int mi = 0; mi < 2; ++mi)
#pragma unroll
        for (int r = 0; r < 16; ++r) {
            int mrow = mi * 32 + (r & 3) + ((r >> 2) << 3) + (khalf << 2);
            bool wok = (wo0 + mrow) < HO;
            float p = 0.f;
#pragma unroll
            for (int ni = 0; ni < 3; ++ni) {
                if (qv[ni] < 169 && wok) {
                    float s = acc[mi][ni][r] + b3v[ni];
                    p += s * Xsh[(rsel + uo[ni]) * 77 + mrow + vo[ni]];
                }
            }
            partial[mi][r] = p;
        }

#pragma unroll
    for (int mi = 0; mi < 2; ++mi)
#pragma unroll
        for (int r = 0; r < 16; ++r) {
            float p = partial[mi][r];
#pragma unroll
            for (int d = 1; d < 32; d <<= 1) p += __shfl_xor(p, d, 64);
            partial[mi][r] = p;
        }

    if (col == 0) {
#pragma unroll
        for (int mi = 0; mi < 2; ++mi)
#pragma unroll
            for (int r = 0; r < 16; ++r) {
                int mrow = mi * 32 + (r & 3) + ((r >> 2) << 3) + (khalf << 2);
                red[wave][mrow] = partial[mi][r];
            }
    }
    __syncthreads();

    if (t < 256) {
        int row_sel = t >> 6, m = t & 63;
        float val = red[row_sel * 2][m] + red[row_sel * 2 + 1][m];
        int wo = wo0 + m, ho = ho0 + row_sel;
        if (wo < HO)
            y[((size_t)b * HO + ho) * HO + wo] = val;
    }
}

extern "C" void kernel_launch(void* const* d_in, const int* in_sizes, int n_in,
                              void* d_out, int out_size, void* d_ws, size_t ws_size,
                              hipStream_t stream) {
    const float* x  = (const float*)d_in[0];
    const float* W1 = (const float*)d_in[1];
    const float* b1 = (const float*)d_in[2];
    const float* W2 = (const float*)d_in[3];
    const float* b2 = (const float*)d_in[4];
    const float* W3 = (const float*)d_in[5];
    const float* b3 = (const float*)d_in[6];
    float* out = (float*)d_out;

    unsigned short* h2  = (unsigned short*)d_ws;
    unsigned short* W2r = h2 + (size_t)BATCH * HW * HW * C;
    unsigned short* W3r = W2r + (size_t)36 * 2 * C * 8;

    repack_w_kernel<<<576, 256, 0, stream>>>(W2, W3, W2r, W3r);
    conv2_fused_kernel<<<dim3(4, 64, 8), 256, 0, stream>>>(x, W1, b1, W2r, b2, h2);
    // conv3 split into two half-batch dispatches (instrumentation): halves land
    // ~65 us so conv2 (single dispatch) contests the top-5 and we finally see
    // its post-fix counters. Math identical to the 242 us r12 version.
    conv3_mfma_kernel<<<dim3(4, 61, 4), 512, 0, stream>>>(x, h2, W3r, b3, out, 0);
    conv3_mfma_kernel<<<dim3(4, 61, 4), 512, 0, stream>>>(x, h2, W3r, b3, out, 4);
}

// Round 16
// 241.480 us; speedup vs baseline: 1.0478x; 1.0478x over previous
//
#include <hip/hip_runtime.h>

#define HW 256
#define BATCH 8
#define C 64
#define HO 244
#define NPAD 192
#define KTOT 576

typedef __bf16 bf16x8 __attribute__((ext_vector_type(8)));
typedef float f32x16 __attribute__((ext_vector_type(16)));
typedef float f32x2 __attribute__((ext_vector_type(2)));
typedef unsigned short us8 __attribute__((ext_vector_type(8)));

// native RNE float->bf16 (v_cvt_pk_bf16_f32 capable)
__device__ inline unsigned short fbf(float f) {
    return __builtin_bit_cast(unsigned short, (__bf16)f);
}

__device__ inline float bf2f(unsigned short s) {
    union { unsigned int u; float f; } c;
    c.u = ((unsigned int)s) << 16;
    return c.f;
}

// ---- merged W2+W3 repack, fragment-coalesced: [((kstep*2+khalf)*N + n)*8 + e] ----
__global__ __launch_bounds__(256) void repack_w_kernel(
    const float* __restrict__ W2, const float* __restrict__ W3,
    unsigned short* __restrict__ B2g, unsigned short* __restrict__ B3g)
{
    int idx = blockIdx.x * 256 + threadIdx.x;
    if (idx < 36 * 2 * C * 8) {
        int e = idx & 7;
        int r = idx >> 3;
        int n = r & 63;
        int s = r >> 6;
        int khalf = s & 1;
        int kstep = s >> 1;
        int chunk = kstep >> 2, ks = kstep & 3;
        int ci = ks * 16 + khalf * 8 + e;
        B2g[idx] = fbf(W2[((size_t)n * C + ci) * 9 + chunk]);
    } else {
        int j = idx - 36 * 2 * C * 8;
        if (j >= 36 * 2 * NPAD * 8) return;
        int e = j & 7;
        int r = j >> 3;
        int n = r % NPAD;
        int s = r / NPAD;
        int khalf = s & 1;
        int kstep = s >> 1;
        int chunk = kstep >> 2, ks = kstep & 3;
        int ci = ks * 16 + khalf * 8 + e;
        float v = (n < 169) ? W3[((size_t)n * C + ci) * 9 + chunk] : 0.f;
        B3g[j] = fbf(v);
    }
}

// ---------------- fused conv1+conv2: depth-2 B prefetch, linear unrolled K ------
__global__ __launch_bounds__(256, 3) void conv2_fused_kernel(
    const float* __restrict__ x, const float* __restrict__ W1,
    const float* __restrict__ b1, const unsigned short* __restrict__ W2r,
    const float* __restrict__ b2, unsigned short* __restrict__ h2)
{
    __shared__ unsigned short Ash[396 * 66];   // 52,272 B
    __shared__ unsigned short Xsh[8 * 68];     //  1,088 B (bf16)

    const int t = threadIdx.x;
    const int lane = t & 63;
    const int wave = t >> 6;
    const int b  = blockIdx.z;
    const int h0 = blockIdx.y * 4;
    const int w0 = blockIdx.x * 64;

    const int col   = lane & 31;
    const int khalf = lane >> 5;
    const int mrow_base = wave * 64;

    // ---- stage x tile (bf16): rows h0-2..h0+5, cols w0-2..w0+65, zero OOB ----
    const float* __restrict__ xplane = x + ((size_t)b << 16);
#pragma unroll
    for (int it = 0; it < 3; ++it) {
        int li = it * 256 + t;
        if (li < 8 * 68) {
            int rr = li / 68, cc = li - rr * 68;
            int hh = h0 - 2 + rr, ww = w0 - 2 + cc;
            bool ok = (hh >= 0) && (hh < HW) && (ww >= 0) && (ww < HW);
            Xsh[li] = ok ? fbf(xplane[hh * HW + ww]) : (unsigned short)0;
        }
    }

    // this thread's 4 channels as two float2 pairs (packed-math path)
    const int g4 = t & 15;
    f32x2 w01[9], w23[9];
    f32x2 bia01, bia23;
    bia01[0] = b1[g4 * 4 + 0]; bia01[1] = b1[g4 * 4 + 1];
    bia23[0] = b1[g4 * 4 + 2]; bia23[1] = b1[g4 * 4 + 3];
#pragma unroll
    for (int q = 0; q < 9; ++q) {
        w01[q][0] = W1[(g4 * 4 + 0) * 9 + q];
        w01[q][1] = W1[(g4 * 4 + 1) * 9 + q];
        w23[q][0] = W1[(g4 * 4 + 2) * 9 + q];
        w23[q][1] = W1[(g4 * 4 + 3) * 9 + q];
    }

    __syncthreads();   // Xsh ready

    // ---- compute h1 tile (conv1 + ReLU + bf16) into Ash ----
    for (int it = 0; it < 25; ++it) {
        int li = it * 256 + t;
        if (li < 6336) {
            int p = li >> 4;
            int pr = p / 66, pc = p - pr * 66;
            int hh = h0 - 1 + pr, ww = w0 - 1 + pc;
            unsigned short ov[4];
            if (hh >= 0 && hh < HW && ww >= 0 && ww < HW) {
                const unsigned short* xb = Xsh + pr * 68 + pc;
                f32x2 a01 = bia01, a23 = bia23;
#pragma unroll
                for (int i = 0; i < 3; ++i)
#pragma unroll
                    for (int j = 0; j < 3; ++j) {
                        float xv = bf2f(xb[i * 68 + j]);
                        f32x2 xv2; xv2[0] = xv; xv2[1] = xv;
                        a01 += xv2 * w01[i * 3 + j];
                        a23 += xv2 * w23[i * 3 + j];
                    }
                ov[0] = fbf(fmaxf(a01[0], 0.f));
                ov[1] = fbf(fmaxf(a01[1], 0.f));
                ov[2] = fbf(fmaxf(a23[0], 0.f));
                ov[3] = fbf(fmaxf(a23[1], 0.f));
            } else {
#pragma unroll
                for (int u = 0; u < 4; ++u) ov[u] = 0;
            }
            *(uint2*)(Ash + p * 66 + g4 * 4) = *(uint2*)ov;
        }
    }

    // depth-2 B pipeline: bcur = kstep, bnx = kstep+1
    const unsigned short* bbase = W2r + ((size_t)khalf * C + col) * 8;
    us8 bcur0 = *(const us8*)(bbase);
    us8 bcur1 = *(const us8*)(bbase + 32 * 8);
    us8 bnx0  = *(const us8*)(bbase + (size_t)(2 * C * 8));
    us8 bnx1  = *(const us8*)(bbase + (size_t)(2 * C * 8) + 32 * 8);

    f32x16 acc[2][2];
#pragma unroll
    for (int ai = 0; ai < 2; ++ai)
#pragma unroll
        for (int nb = 0; nb < 2; ++nb)
#pragma unroll
            for (int r = 0; r < 16; ++r) acc[ai][nb][r] = 0.f;

    __syncthreads();   // Ash ready

#pragma unroll
    for (int kstep = 0; kstep < 36; ++kstep) {
        const int chunk = kstep >> 2, ks = kstep & 3;
        const int ii = chunk / 3, jj = chunk - ii * 3;
        const int pixbase = (wave + ii) * 66 + jj;
        us8 bn0, bn1;
        if (kstep + 2 < 36) {
            const unsigned short* bp = bbase + (size_t)(kstep + 2) * (2 * C * 8);
            bn0 = *(const us8*)(bp);
            bn1 = *(const us8*)(bp + 32 * 8);
        }
        const int koff = ks * 16 + khalf * 8;
        bf16x8 a0 = __builtin_bit_cast(bf16x8, *(const us8*)(Ash + (pixbase + col) * 66 + koff));
        bf16x8 a1 = __builtin_bit_cast(bf16x8, *(const us8*)(Ash + (pixbase + col + 32) * 66 + koff));
        bf16x8 v0 = __builtin_bit_cast(bf16x8, bcur0);
        bf16x8 v1 = __builtin_bit_cast(bf16x8, bcur1);
        acc[0][0] = __builtin_amdgcn_mfma_f32_32x32x16_bf16(a0, v0, acc[0][0], 0, 0, 0);
        acc[0][1] = __builtin_amdgcn_mfma_f32_32x32x16_bf16(a0, v1, acc[0][1], 0, 0, 0);
        acc[1][0] = __builtin_amdgcn_mfma_f32_32x32x16_bf16(a1, v0, acc[1][0], 0, 0, 0);
        acc[1][1] = __builtin_amdgcn_mfma_f32_32x32x16_bf16(a1, v1, acc[1][1], 0, 0, 0);
        bcur0 = bnx0; bcur1 = bnx1;
        bnx0 = bn0; bnx1 = bn1;
    }

#pragma unroll
    for (int nb = 0; nb < 2; ++nb) {
        const int n = nb * 32 + col;
        const float bias = b2[n];
#pragma unroll
        for (int ai = 0; ai < 2; ++ai) {
#pragma unroll
            for (int r = 0; r < 16; ++r) {
                int m = mrow_base + ai * 32 + (r & 3) + ((r >> 2) << 3) + (khalf << 2);
                int h = h0 + (m >> 6), w = w0 + (m & 63);
                float val = fmaxf(acc[ai][nb][r] + bias, 0.f);
                h2[(((size_t)b * HW + h) * HW + w) * C + n] = fbf(val);
            }
        }
    }
}

// ---------------- conv3 + NLM: depth-2 B prefetch, linear unrolled K -----------
__global__ __launch_bounds__(512, 3) void conv3_mfma_kernel(
    const float* __restrict__ x, const unsigned short* __restrict__ h2,
    const unsigned short* __restrict__ Bg, const float* __restrict__ b3,
    float* __restrict__ y)
{
    __shared__ unsigned short Ash[396 * 72];
    __shared__ float Xsh[16 * 77];
    __shared__ float red[8][64];

    const int t = threadIdx.x;
    const int lane = t & 63;
    const int wave = t >> 6;
    const int b   = blockIdx.z;
    const int ho0 = blockIdx.y * 4;
    const int wo0 = blockIdx.x * 64;

    const int col   = lane & 31;
    const int khalf = lane >> 5;
    const int rsel      = wave >> 1;
    const int mrow_base = rsel * 64;
    const int nbase     = (wave & 1) * 96;

    f32x16 acc[2][3];
#pragma unroll
    for (int mi = 0; mi < 2; ++mi)
#pragma unroll
        for (int ni = 0; ni < 3; ++ni)
#pragma unroll
            for (int r = 0; r < 16; ++r) acc[mi][ni][r] = 0.f;

#pragma unroll
    for (int it = 0; it < 7; ++it) {
        int li = it * 512 + t;
        if (li < 396 * 8) {
            int p = li >> 3, g = li & 7;
            int row = p / 66, cl = p - row * 66;
            int ww = wo0 + 5 + cl; ww = ww < 255 ? ww : 255;
            size_t src = (((size_t)b * HW + (ho0 + 5 + row)) * HW + ww) * C + g * 8;
            *(uint4*)(Ash + p * 72 + g * 8) = *(const uint4*)(h2 + src);
        }
    }
    {
        const float* __restrict__ xplane = x + ((size_t)b << 16);
#pragma unroll
        for (int it = 0; it < 3; ++it) {
            int li = it * 512 + t;
            if (li < 16 * 76) {
                int rr = li / 76, cc = li - rr * 76;
                int ww = wo0 + cc; ww = ww < 255 ? ww : 255;
                Xsh[rr * 77 + cc] = xplane[(ho0 + rr) * HW + ww];
            }
        }
    }

    // depth-2 B pipeline: bcur = kstep, bnx = kstep+1
    const unsigned short* bbase = Bg + ((size_t)khalf * NPAD + nbase + col) * 8;
    us8 bcur0 = *(const us8*)(bbase);
    us8 bcur1 = *(const us8*)(bbase + 32 * 8);
    us8 bcur2 = *(const us8*)(bbase + 64 * 8);
    us8 bnx0  = *(const us8*)(bbase + (size_t)(2 * NPAD * 8));
    us8 bnx1  = *(const us8*)(bbase + (size_t)(2 * NPAD * 8) + 32 * 8);
    us8 bnx2  = *(const us8*)(bbase + (size_t)(2 * NPAD * 8) + 64 * 8);

    __syncthreads();

#pragma unroll
    for (int kstep = 0; kstep < 36; ++kstep) {
        const int chunk = kstep >> 2, ks = kstep & 3;
        const int ii = chunk / 3, jj = chunk - ii * 3;
        const int pixbase = (rsel + ii) * 66 + jj;
        us8 bn0, bn1, bn2;
        if (kstep + 2 < 36) {
            const unsigned short* bp = bbase + (size_t)(kstep + 2) * (2 * NPAD * 8);
            bn0 = *(const us8*)(bp);
            bn1 = *(const us8*)(bp + 32 * 8);
            bn2 = *(const us8*)(bp + 64 * 8);
        }
        const int koff = ks * 16 + khalf * 8;
        bf16x8 a0 = __builtin_bit_cast(bf16x8, *(const us8*)(Ash + (pixbase + col) * 72 + koff));
        bf16x8 a1 = __builtin_bit_cast(bf16x8, *(const us8*)(Ash + (pixbase + col + 32) * 72 + koff));
        bf16x8 v0 = __builtin_bit_cast(bf16x8, bcur0);
        bf16x8 v1 = __builtin_bit_cast(bf16x8, bcur1);
        bf16x8 v2 = __builtin_bit_cast(bf16x8, bcur2);
        acc[0][0] = __builtin_amdgcn_mfma_f32_32x32x16_bf16(a0, v0, acc[0][0], 0, 0, 0);
        acc[0][1] = __builtin_amdgcn_mfma_f32_32x32x16_bf16(a0, v1, acc[0][1], 0, 0, 0);
        acc[0][2] = __builtin_amdgcn_mfma_f32_32x32x16_bf16(a0, v2, acc[0][2], 0, 0, 0);
        acc[1][0] = __builtin_amdgcn_mfma_f32_32x32x16_bf16(a1, v0, acc[1][0], 0, 0, 0);
        acc[1][1] = __builtin_amdgcn_mfma_f32_32x32x16_bf16(a1, v1, acc[1][1], 0, 0, 0);
        acc[1][2] = __builtin_amdgcn_mfma_f32_32x32x16_bf16(a1, v2, acc[1][2], 0, 0, 0);
        bcur0 = bnx0; bcur1 = bnx1; bcur2 = bnx2;
        bnx0 = bn0; bnx1 = bn1; bnx2 = bn2;
    }

    int   qv[3], uo[3], vo[3];
    float b3v[3];
#pragma unroll
    for (int ni = 0; ni < 3; ++ni) {
        int q = nbase + ni * 32 + col;
        qv[ni] = q;
        int u = q / 13;
        uo[ni] = u;
        vo[ni] = q - u * 13;
        b3v[ni] = (q < 169) ? b3[q] : 0.f;
    }

    float partial[2][16];
#pragma unroll
    for (int mi = 0; mi < 2; ++mi)
#pragma unroll
        for (int r = 0; r < 16; ++r) {
            int mrow = mi * 32 + (r & 3) + ((r >> 2) << 3) + (khalf << 2);
            bool wok = (wo0 + mrow) < HO;
            float p = 0.f;
#pragma unroll
            for (int ni = 0; ni < 3; ++ni) {
                if (qv[ni] < 169 && wok) {
                    float s = acc[mi][ni][r] + b3v[ni];
                    p += s * Xsh[(rsel + uo[ni]) * 77 + mrow + vo[ni]];
                }
            }
            partial[mi][r] = p;
        }

#pragma unroll
    for (int mi = 0; mi < 2; ++mi)
#pragma unroll
        for (int r = 0; r < 16; ++r) {
            float p = partial[mi][r];
#pragma unroll
            for (int d = 1; d < 32; d <<= 1) p += __shfl_xor(p, d, 64);
            partial[mi][r] = p;
        }

    if (col == 0) {
#pragma unroll
        for (int mi = 0; mi < 2; ++mi)
#pragma unroll
            for (int r = 0; r < 16; ++r) {
                int mrow = mi * 32 + (r & 3) + ((r >> 2) << 3) + (khalf << 2);
                red[wave][mrow] = partial[mi][r];
            }
    }
    __syncthreads();

    if (t < 256) {
        int row_sel = t >> 6, m = t & 63;
        float val = red[row_sel * 2][m] + red[row_sel * 2 + 1][m];
        int wo = wo0 + m, ho = ho0 + row_sel;
        if (wo < HO)
            y[((size_t)b * HO + ho) * HO + wo] = val;
    }
}

extern "C" void kernel_launch(void* const* d_in, const int* in_sizes, int n_in,
                              void* d_out, int out_size, void* d_ws, size_t ws_size,
                              hipStream_t stream) {
    const float* x  = (const float*)d_in[0];
    const float* W1 = (const float*)d_in[1];
    const float* b1 = (const float*)d_in[2];
    const float* W2 = (const float*)d_in[3];
    const float* b2 = (const float*)d_in[4];
    const float* W3 = (const float*)d_in[5];
    const float* b3 = (const float*)d_in[6];
    float* out = (float*)d_out;

    unsigned short* h2  = (unsigned short*)d_ws;
    unsigned short* W2r = h2 + (size_t)BATCH * HW * HW * C;
    unsigned short* W3r = W2r + (size_t)36 * 2 * C * 8;

    repack_w_kernel<<<576, 256, 0, stream>>>(W2, W3, W2r, W3r);
    conv2_fused_kernel<<<dim3(4, 64, 8), 256, 0, stream>>>(x, W1, b1, W2r, b2, h2);
    conv3_mfma_kernel<<<dim3(4, 61, 8), 512, 0, stream>>>(x, h2, W3r, b3, out);
}